// Round 1
// baseline (775.117 us; speedup 1.0000x reference)
//
#include <hip/hip_runtime.h>
#include <hip/hip_bf16.h>

#define N_NODES 50000
#define N_EDGES 800000
#define DIM 64

// ---------- helpers ----------
__device__ __forceinline__ float bf2f(unsigned short u) {
  return __uint_as_float(((unsigned int)u) << 16);
}
__device__ __forceinline__ unsigned short f2bf(float f) {
  unsigned int x = __float_as_uint(f);
  unsigned int r = (x + 0x7fffu + ((x >> 16) & 1u)) >> 16;  // RNE
  return (unsigned short)r;
}

// ---------- dtype detection (flags[0]=bf16 inputs, flags[1]=int64 indices) ----------
__global__ void k_detect(const unsigned short* __restrict__ feat,
                         const unsigned int* __restrict__ eidx,
                         int* __restrict__ flags) {
  int lane = threadIdx.x;  // 64 threads
  // If features are fp32, the EVEN 16-bit halves are low mantissa bits ->
  // random exponents when viewed as bf16 -> ~half have |v| >= 1000.
  float v = bf2f(feat[2 * lane]);
  bool big = !(fabsf(v) < 1000.0f);  // catches inf/nan too
  unsigned long long bb = __ballot(big);
  // If edge_index is int64 (values < 50000), every odd 32-bit word is 0.
  unsigned int w = eidx[2 * lane + 1];
  unsigned long long bz = __ballot(w == 0u);
  if (lane == 0) {
    flags[0] = (__popcll(bb) < 8) ? 1 : 0;
    flags[1] = (__popcll(bz) == 64) ? 1 : 0;
  }
}

__device__ __forceinline__ int eidx_at(const int* __restrict__ p, int k, int i64) {
  return p[i64 ? (k << 1) : k];
}

// ---------- CSR build ----------
__global__ void k_count(const int* __restrict__ eidx, const int* __restrict__ flags,
                        int* __restrict__ cnt) {
  int e = blockIdx.x * blockDim.x + threadIdx.x;
  if (e >= N_EDGES) return;
  int d = eidx_at(eidx, N_EDGES + e, flags[1]);
  atomicAdd(&cnt[d], 1);
}

__global__ void k_scan(const int* __restrict__ cnt, int* __restrict__ rowp) {
  __shared__ int part[256];
  __shared__ int tot;
  int t = threadIdx.x;
  const int C = (N_NODES + 255) / 256;
  int lo = t * C;
  int hi = lo + C; if (hi > N_NODES) hi = N_NODES;
  int s = 0;
  for (int i = lo; i < hi; ++i) s += cnt[i];
  part[t] = s;
  __syncthreads();
  if (t == 0) {
    int run = 0;
    for (int i = 0; i < 256; ++i) { int v = part[i]; part[i] = run; run += v; }
    tot = run;
  }
  __syncthreads();
  int run = part[t];
  for (int i = lo; i < hi; ++i) { rowp[i] = run; run += cnt[i]; }
  if (t == 0) rowp[N_NODES] = tot;
}

__global__ void k_fill(const int* __restrict__ eidx, const int* __restrict__ flags,
                       const int* __restrict__ rowp, int* __restrict__ cur,
                       int* __restrict__ csr) {
  int e = blockIdx.x * blockDim.x + threadIdx.x;
  if (e >= N_EDGES) return;
  int i64 = flags[1];
  int d = eidx_at(eidx, N_EDGES + e, i64);
  int s = eidx_at(eidx, e, i64);
  int pos = rowp[d] + atomicAdd(&cur[d], 1);
  csr[pos] = s;
}

// ---------- input conversion to fp32 working buffer ----------
__global__ void k_cvt(const void* __restrict__ feat, const int* __restrict__ flags,
                      float* __restrict__ out) {
  int i = blockIdx.x * blockDim.x + threadIdx.x;
  if (i >= N_NODES * DIM) return;
  out[i] = flags[0] ? bf2f(((const unsigned short*)feat)[i])
                    : ((const float*)feat)[i];
}

// ---------- h = x@W, s_src = h@a_s, s_dst = h@a_d ----------
__global__ __launch_bounds__(256) void k_gemm(
    const float* __restrict__ x, const void* __restrict__ Wv,
    const void* __restrict__ asv, const void* __restrict__ adv, int head,
    const int* __restrict__ flags, float* __restrict__ h,
    float* __restrict__ ss, float* __restrict__ sd) {
  const int bf = flags[0];
  const int lane = threadIdx.x & 63;
  const int wid = blockIdx.x * (blockDim.x >> 6) + (threadIdx.x >> 6);
  const int nw = gridDim.x * (blockDim.x >> 6);
  float wcol[DIM];
  float a_s, a_d;
  if (bf) {
    const unsigned short* W = (const unsigned short*)Wv + head * DIM * DIM;
    const unsigned short* pa = (const unsigned short*)asv + head * DIM;
    const unsigned short* pd = (const unsigned short*)adv + head * DIM;
#pragma unroll
    for (int k = 0; k < DIM; ++k) wcol[k] = bf2f(W[k * DIM + lane]);
    a_s = bf2f(pa[lane]); a_d = bf2f(pd[lane]);
  } else {
    const float* W = (const float*)Wv + head * DIM * DIM;
    const float* pa = (const float*)asv + head * DIM;
    const float* pd = (const float*)adv + head * DIM;
#pragma unroll
    for (int k = 0; k < DIM; ++k) wcol[k] = W[k * DIM + lane];
    a_s = pa[lane]; a_d = pd[lane];
  }
  for (int row = wid; row < N_NODES; row += nw) {
    const float4* xr = (const float4*)(x + row * DIM);
    float acc = 0.f;
#pragma unroll
    for (int q = 0; q < DIM / 4; ++q) {
      float4 xv = xr[q];
      acc = fmaf(xv.x, wcol[4 * q + 0], acc);
      acc = fmaf(xv.y, wcol[4 * q + 1], acc);
      acc = fmaf(xv.z, wcol[4 * q + 2], acc);
      acc = fmaf(xv.w, wcol[4 * q + 3], acc);
    }
    h[row * DIM + lane] = acc;
    float u = acc * a_s, v = acc * a_d;
#pragma unroll
    for (int off = 32; off > 0; off >>= 1) {
      u += __shfl_xor(u, off);
      v += __shfl_xor(v, off);
    }
    if (lane == 0) { ss[row] = u; sd[row] = v; }
  }
}

// ---------- per-dst-node softmax aggregation (one wave per node) ----------
__global__ __launch_bounds__(256) void k_agg(
    const float* __restrict__ h, const float* __restrict__ ss,
    const float* __restrict__ sd, const int* __restrict__ rowp,
    const int* __restrict__ csr, float* __restrict__ out_f,
    void* __restrict__ out_final, const int* __restrict__ flags,
    int do_elu, int is_final) {
  __shared__ __align__(16) float lp[4][64];
  __shared__ __align__(16) int lsrc[4][64];
  const int lane = threadIdx.x & 63;
  const int w = threadIdx.x >> 6;
  const int node = blockIdx.x * 4 + w;
  const int base = rowp[node];
  const int deg = rowp[node + 1] - base;
  const float sdn = sd[node];

  // pass 1: segment max
  float m = -INFINITY;
  for (int j = lane; j < deg; j += 64) {
    int s = csr[base + j];
    float sc = ss[s] + sdn;
    sc = sc >= 0.f ? sc : 0.2f * sc;
    m = fmaxf(m, sc);
  }
#pragma unroll
  for (int off = 32; off > 0; off >>= 1) m = fmaxf(m, __shfl_xor(m, off));

  // pass 2: unnormalized weighted accumulate, chunked by 64 edges
  float acc = 0.f, z = 0.f;
  for (int c = 0; c < deg; c += 64) {
    int j = c + lane;
    float p = 0.f; int s = 0;
    if (j < deg) {
      s = csr[base + j];
      float sc = ss[s] + sdn;
      sc = sc >= 0.f ? sc : 0.2f * sc;
      p = __expf(sc - m);
    }
    lp[w][lane] = p;
    lsrc[w][lane] = s;
    __builtin_amdgcn_wave_barrier();  // wave-synchronous LDS (per-wave slice)
    z += p;
    const int cl = (deg - c < 64) ? (deg - c) : 64;
    const int q4 = (cl + 3) >> 2;  // tail entries have p=0, s=0 -> contribute 0
    const float4* lp4 = (const float4*)(&lp[w][0]);
    const int4* ls4 = (const int4*)(&lsrc[w][0]);
    for (int q = 0; q < q4; ++q) {
      float4 pv = lp4[q];
      int4 sv = ls4[q];
      acc = fmaf(pv.x, h[sv.x * DIM + lane], acc);
      acc = fmaf(pv.y, h[sv.y * DIM + lane], acc);
      acc = fmaf(pv.z, h[sv.z * DIM + lane], acc);
      acc = fmaf(pv.w, h[sv.w * DIM + lane], acc);
    }
    __builtin_amdgcn_wave_barrier();
  }
#pragma unroll
  for (int off = 32; off > 0; off >>= 1) z += __shfl_xor(z, off);

  float o = acc / (z + 1e-16f);  // deg==0 -> 0/1e-16 = 0, matches reference
  if (do_elu) o = (o > 0.f) ? o : expm1f(o);
  if (is_final) {
    if (flags[0]) ((unsigned short*)out_final)[node * DIM + lane] = f2bf(o);
    else          ((float*)out_final)[node * DIM + lane] = o;
  } else {
    out_f[node * DIM + lane] = o;
  }
}

// ---------- launch ----------
extern "C" void kernel_launch(void* const* d_in, const int* in_sizes, int n_in,
                              void* d_out, int out_size, void* d_ws, size_t ws_size,
                              hipStream_t stream) {
  const void* feat = d_in[0];
  const int* eidx = (const int*)d_in[1];

  float* bufA = (float*)d_ws;                    // N*64 fp32
  float* bufB = bufA + N_NODES * DIM;            // N*64 fp32
  float* hbuf = bufB + N_NODES * DIM;            // N*64 fp32
  float* ssrc = hbuf + N_NODES * DIM;            // N
  float* sdst = ssrc + N_NODES;                  // N
  int* rowp = (int*)(sdst + N_NODES);            // N+1
  int* cnt  = rowp + N_NODES + 1;                // N (also cursor)
  int* csr  = cnt + N_NODES;                     // E
  int* flags = csr + N_EDGES;                    // 2

  k_detect<<<1, 64, 0, stream>>>((const unsigned short*)feat,
                                 (const unsigned int*)eidx, flags);
  (void)hipMemsetAsync(cnt, 0, N_NODES * sizeof(int), stream);
  k_count<<<(N_EDGES + 255) / 256, 256, 0, stream>>>(eidx, flags, cnt);
  k_scan<<<1, 256, 0, stream>>>(cnt, rowp);
  (void)hipMemsetAsync(cnt, 0, N_NODES * sizeof(int), stream);
  k_fill<<<(N_EDGES + 255) / 256, 256, 0, stream>>>(eidx, flags, rowp, cnt, csr);
  k_cvt<<<(N_NODES * DIM + 255) / 256, 256, 0, stream>>>(feat, flags, bufA);

  float* cur = bufA;
  float* nxt = bufB;
  for (int i = 0; i < 8; ++i) {
    const void* Wb = (i < 4) ? d_in[2] : d_in[5];
    const void* ab = (i < 4) ? d_in[3] : d_in[6];
    const void* db = (i < 4) ? d_in[4] : d_in[7];
    int head = i & 3;
    k_gemm<<<1024, 256, 0, stream>>>(cur, Wb, ab, db, head, flags, hbuf, ssrc, sdst);
    int elu = (i == 3 || i == 7) ? 1 : 0;
    int fin = (i == 7) ? 1 : 0;
    k_agg<<<N_NODES / 4, 256, 0, stream>>>(hbuf, ssrc, sdst, rowp, csr, nxt,
                                           d_out, flags, elu, fin);
    float* t = cur; cur = nxt; nxt = t;
  }
}

// Round 2
// 687.697 us; speedup vs baseline: 1.1271x; 1.1271x over previous
//
#include <hip/hip_runtime.h>
#include <hip/hip_bf16.h>

#define N_NODES 50000
#define N_EDGES 800000
#define DIM 64
#define SCAN_BLOCKS ((N_NODES + 255) / 256)  // 196

// ---------- helpers ----------
__device__ __forceinline__ float bf2f(unsigned short u) {
  return __uint_as_float(((unsigned int)u) << 16);
}
__device__ __forceinline__ unsigned short f2bf(float f) {
  unsigned int x = __float_as_uint(f);
  unsigned int r = (x + 0x7fffu + ((x >> 16) & 1u)) >> 16;  // RNE
  return (unsigned short)r;
}

// ---------- dtype detection (flags[0]=bf16 inputs, flags[1]=int64 indices) ----------
__global__ void k_detect(const unsigned short* __restrict__ feat,
                         const unsigned int* __restrict__ eidx,
                         int* __restrict__ flags) {
  int lane = threadIdx.x;  // 64 threads
  float v = bf2f(feat[2 * lane]);
  bool big = !(fabsf(v) < 1000.0f);
  unsigned long long bb = __ballot(big);
  unsigned int w = eidx[2 * lane + 1];
  unsigned long long bz = __ballot(w == 0u);
  if (lane == 0) {
    flags[0] = (__popcll(bb) < 8) ? 1 : 0;
    flags[1] = (__popcll(bz) == 64) ? 1 : 0;
  }
}

__device__ __forceinline__ int eidx_at(const int* __restrict__ p, int k, int i64) {
  return p[i64 ? (k << 1) : k];
}

// ---------- CSR build ----------
__global__ void k_count(const int* __restrict__ eidx, const int* __restrict__ flags,
                        int* __restrict__ cnt) {
  int e = blockIdx.x * blockDim.x + threadIdx.x;
  if (e >= N_EDGES) return;
  int d = eidx_at(eidx, N_EDGES + e, flags[1]);
  atomicAdd(&cnt[d], 1);
}

// parallel exclusive scan: per-block scan -> scan of block sums -> add offsets
__global__ void k_scan1(const int* __restrict__ cnt, int* __restrict__ rowp,
                        int* __restrict__ bsum) {
  __shared__ int sm[256];
  int t = threadIdx.x, b = blockIdx.x, i = b * 256 + t;
  int v = (i < N_NODES) ? cnt[i] : 0;
  sm[t] = v;
  __syncthreads();
  for (int off = 1; off < 256; off <<= 1) {
    int x = (t >= off) ? sm[t - off] : 0;
    __syncthreads();
    sm[t] += x;
    __syncthreads();
  }
  if (i < N_NODES) rowp[i] = sm[t] - v;  // exclusive, block-local
  if (t == 255) bsum[b] = sm[t];
}

__global__ void k_scan2(int* __restrict__ bsum) {
  __shared__ int sm[256];
  int t = threadIdx.x;
  int v = (t < SCAN_BLOCKS) ? bsum[t] : 0;
  sm[t] = v;
  __syncthreads();
  for (int off = 1; off < 256; off <<= 1) {
    int x = (t >= off) ? sm[t - off] : 0;
    __syncthreads();
    sm[t] += x;
    __syncthreads();
  }
  if (t < SCAN_BLOCKS) bsum[t] = sm[t] - v;  // exclusive block offsets
}

__global__ void k_scan3(int* __restrict__ rowp, const int* __restrict__ bsum) {
  int t = threadIdx.x, b = blockIdx.x, i = b * 256 + t;
  if (i < N_NODES) rowp[i] += bsum[b];
  if (i == 0) rowp[N_NODES] = N_EDGES;
}

__global__ void k_fill(const int* __restrict__ eidx, const int* __restrict__ flags,
                       const int* __restrict__ rowp, int* __restrict__ cur,
                       int* __restrict__ csr) {
  int e = blockIdx.x * blockDim.x + threadIdx.x;
  if (e >= N_EDGES) return;
  int i64 = flags[1];
  int d = eidx_at(eidx, N_EDGES + e, i64);
  int s = eidx_at(eidx, e, i64);
  int pos = rowp[d] + atomicAdd(&cur[d], 1);
  csr[pos] = s;
}

// ---------- input conversion to fp32 working buffer ----------
__global__ void k_cvt(const void* __restrict__ feat, const int* __restrict__ flags,
                      float* __restrict__ out) {
  int i = blockIdx.x * blockDim.x + threadIdx.x;
  if (i >= N_NODES * DIM) return;
  out[i] = flags[0] ? bf2f(((const unsigned short*)feat)[i])
                    : ((const float*)feat)[i];
}

// ---------- h = x@W, s_src = h@a_s, s_dst = h@a_d ----------
__global__ __launch_bounds__(256) void k_gemm(
    const float* __restrict__ x, const void* __restrict__ Wv,
    const void* __restrict__ asv, const void* __restrict__ adv, int head,
    const int* __restrict__ flags, float* __restrict__ h,
    float* __restrict__ ss, float* __restrict__ sd) {
  const int bf = flags[0];
  const int lane = threadIdx.x & 63;
  const int wid = blockIdx.x * (blockDim.x >> 6) + (threadIdx.x >> 6);
  const int nw = gridDim.x * (blockDim.x >> 6);
  float wcol[DIM];
  float a_s, a_d;
  if (bf) {
    const unsigned short* W = (const unsigned short*)Wv + head * DIM * DIM;
    const unsigned short* pa = (const unsigned short*)asv + head * DIM;
    const unsigned short* pd = (const unsigned short*)adv + head * DIM;
#pragma unroll
    for (int k = 0; k < DIM; ++k) wcol[k] = bf2f(W[k * DIM + lane]);
    a_s = bf2f(pa[lane]); a_d = bf2f(pd[lane]);
  } else {
    const float* W = (const float*)Wv + head * DIM * DIM;
    const float* pa = (const float*)asv + head * DIM;
    const float* pd = (const float*)adv + head * DIM;
#pragma unroll
    for (int k = 0; k < DIM; ++k) wcol[k] = W[k * DIM + lane];
    a_s = pa[lane]; a_d = pd[lane];
  }
  for (int row = wid; row < N_NODES; row += nw) {
    const float4* xr = (const float4*)(x + row * DIM);
    float acc = 0.f;
#pragma unroll
    for (int q = 0; q < DIM / 4; ++q) {
      float4 xv = xr[q];
      acc = fmaf(xv.x, wcol[4 * q + 0], acc);
      acc = fmaf(xv.y, wcol[4 * q + 1], acc);
      acc = fmaf(xv.z, wcol[4 * q + 2], acc);
      acc = fmaf(xv.w, wcol[4 * q + 3], acc);
    }
    h[row * DIM + lane] = acc;
    float u = acc * a_s, v = acc * a_d;
#pragma unroll
    for (int off = 32; off > 0; off >>= 1) {
      u += __shfl_xor(u, off);
      v += __shfl_xor(v, off);
    }
    if (lane == 0) { ss[row] = u; sd[row] = v; }
  }
}

// ---------- per-dst-node softmax aggregation (one wave per node) ----------
__global__ __launch_bounds__(256) void k_agg(
    const float* __restrict__ h, const float* __restrict__ ss,
    const float* __restrict__ sd, const int* __restrict__ rowp,
    const int* __restrict__ csr, float* __restrict__ out_f,
    void* __restrict__ out_final, const int* __restrict__ flags,
    int do_elu, int is_final) {
  __shared__ __align__(16) float lp[4][64];
  __shared__ __align__(16) int lsrc[4][64];
  const int lane = threadIdx.x & 63;
  const int w = threadIdx.x >> 6;
  const int node = blockIdx.x * 4 + w;
  const int base = rowp[node];
  const int deg = rowp[node + 1] - base;
  const float sdn = sd[node];

  float acc = 0.f, z;
  if (deg <= 64) {
    // fast path: one gather of csr/ss, scores held in registers
    int s = 0;
    float sc = -INFINITY;
    if (lane < deg) {
      s = csr[base + lane];
      float t = ss[s] + sdn;
      sc = t >= 0.f ? t : 0.2f * t;
    }
    float m = sc;
#pragma unroll
    for (int off = 32; off > 0; off >>= 1) m = fmaxf(m, __shfl_xor(m, off));
    float p = (lane < deg) ? __expf(sc - m) : 0.f;
    z = p;
#pragma unroll
    for (int off = 32; off > 0; off >>= 1) z += __shfl_xor(z, off);
    lp[w][lane] = p;
    lsrc[w][lane] = s;
    __builtin_amdgcn_wave_barrier();
    const int q4 = (deg + 3) >> 2;  // tail p=0, s=0 -> contributes 0
    const float4* lp4 = (const float4*)(&lp[w][0]);
    const int4* ls4 = (const int4*)(&lsrc[w][0]);
    for (int q = 0; q < q4; ++q) {
      float4 pv = lp4[q];
      int4 sv = ls4[q];
      acc = fmaf(pv.x, h[sv.x * DIM + lane], acc);
      acc = fmaf(pv.y, h[sv.y * DIM + lane], acc);
      acc = fmaf(pv.z, h[sv.z * DIM + lane], acc);
      acc = fmaf(pv.w, h[sv.w * DIM + lane], acc);
    }
    __builtin_amdgcn_wave_barrier();
  } else {
    // generic chunked path (rare: deg > 64)
    float m = -INFINITY;
    for (int j = lane; j < deg; j += 64) {
      int s = csr[base + j];
      float sc = ss[s] + sdn;
      sc = sc >= 0.f ? sc : 0.2f * sc;
      m = fmaxf(m, sc);
    }
#pragma unroll
    for (int off = 32; off > 0; off >>= 1) m = fmaxf(m, __shfl_xor(m, off));
    z = 0.f;
    for (int c = 0; c < deg; c += 64) {
      int j = c + lane;
      float p = 0.f; int s = 0;
      if (j < deg) {
        int sv = csr[base + j];
        s = sv;
        float sc = ss[sv] + sdn;
        sc = sc >= 0.f ? sc : 0.2f * sc;
        p = __expf(sc - m);
      }
      lp[w][lane] = p;
      lsrc[w][lane] = s;
      __builtin_amdgcn_wave_barrier();
      z += p;
      const int cl = (deg - c < 64) ? (deg - c) : 64;
      const int q4 = (cl + 3) >> 2;
      const float4* lp4 = (const float4*)(&lp[w][0]);
      const int4* ls4 = (const int4*)(&lsrc[w][0]);
      for (int q = 0; q < q4; ++q) {
        float4 pv = lp4[q];
        int4 sv = ls4[q];
        acc = fmaf(pv.x, h[sv.x * DIM + lane], acc);
        acc = fmaf(pv.y, h[sv.y * DIM + lane], acc);
        acc = fmaf(pv.z, h[sv.z * DIM + lane], acc);
        acc = fmaf(pv.w, h[sv.w * DIM + lane], acc);
      }
      __builtin_amdgcn_wave_barrier();
    }
#pragma unroll
    for (int off = 32; off > 0; off >>= 1) z += __shfl_xor(z, off);
  }

  float o = acc / (z + 1e-16f);  // deg==0 -> 0, matches reference
  if (do_elu) o = (o > 0.f) ? o : expm1f(o);
  if (is_final) {
    if (flags[0]) ((unsigned short*)out_final)[node * DIM + lane] = f2bf(o);
    else          ((float*)out_final)[node * DIM + lane] = o;
  } else {
    out_f[node * DIM + lane] = o;
  }
}

// ---------- launch ----------
extern "C" void kernel_launch(void* const* d_in, const int* in_sizes, int n_in,
                              void* d_out, int out_size, void* d_ws, size_t ws_size,
                              hipStream_t stream) {
  const void* feat = d_in[0];
  const int* eidx = (const int*)d_in[1];

  float* bufA = (float*)d_ws;                    // N*64 fp32
  float* bufB = bufA + N_NODES * DIM;            // N*64 fp32
  float* hbuf = bufB + N_NODES * DIM;            // N*64 fp32
  float* ssrc = hbuf + N_NODES * DIM;            // N
  float* sdst = ssrc + N_NODES;                  // N
  int* rowp = (int*)(sdst + N_NODES);            // N+1
  int* cnt  = rowp + N_NODES + 1;                // N (also cursor)
  int* csr  = cnt + N_NODES;                     // E
  int* bsum = csr + N_EDGES;                     // SCAN_BLOCKS
  int* flags = bsum + SCAN_BLOCKS;               // 2

  k_detect<<<1, 64, 0, stream>>>((const unsigned short*)feat,
                                 (const unsigned int*)eidx, flags);
  (void)hipMemsetAsync(cnt, 0, N_NODES * sizeof(int), stream);
  k_count<<<(N_EDGES + 255) / 256, 256, 0, stream>>>(eidx, flags, cnt);
  k_scan1<<<SCAN_BLOCKS, 256, 0, stream>>>(cnt, rowp, bsum);
  k_scan2<<<1, 256, 0, stream>>>(bsum);
  k_scan3<<<SCAN_BLOCKS, 256, 0, stream>>>(rowp, bsum);
  (void)hipMemsetAsync(cnt, 0, N_NODES * sizeof(int), stream);
  k_fill<<<(N_EDGES + 255) / 256, 256, 0, stream>>>(eidx, flags, rowp, cnt, csr);
  k_cvt<<<(N_NODES * DIM + 255) / 256, 256, 0, stream>>>(feat, flags, bufA);

  float* cur = bufA;
  float* nxt = bufB;
  for (int i = 0; i < 8; ++i) {
    const void* Wb = (i < 4) ? d_in[2] : d_in[5];
    const void* ab = (i < 4) ? d_in[3] : d_in[6];
    const void* db = (i < 4) ? d_in[4] : d_in[7];
    int head = i & 3;
    k_gemm<<<1024, 256, 0, stream>>>(cur, Wb, ab, db, head, flags, hbuf, ssrc, sdst);
    int elu = (i == 3 || i == 7) ? 1 : 0;
    int fin = (i == 7) ? 1 : 0;
    k_agg<<<N_NODES / 4, 256, 0, stream>>>(hbuf, ssrc, sdst, rowp, csr, nxt,
                                           d_out, flags, elu, fin);
    float* t = cur; cur = nxt; nxt = t;
  }
}

// Round 3
// 627.720 us; speedup vs baseline: 1.2348x; 1.0955x over previous
//
#include <hip/hip_runtime.h>
#include <hip/hip_bf16.h>

#define N_NODES 50000
#define N_EDGES 800000
#define DIM 64
#define SCAN_BLOCKS ((N_NODES + 255) / 256)  // 196

// ---------- helpers ----------
__device__ __forceinline__ float bf2f(unsigned short u) {
  return __uint_as_float(((unsigned int)u) << 16);
}
__device__ __forceinline__ unsigned short f2bf(float f) {
  unsigned int x = __float_as_uint(f);
  unsigned int r = (x + 0x7fffu + ((x >> 16) & 1u)) >> 16;  // RNE
  return (unsigned short)r;
}

// ---------- dtype detection (flags[0]=bf16 inputs, flags[1]=int64 indices) ----------
__global__ void k_detect(const unsigned short* __restrict__ feat,
                         const unsigned int* __restrict__ eidx,
                         int* __restrict__ flags) {
  int lane = threadIdx.x;  // 64 threads
  float v = bf2f(feat[2 * lane]);
  bool big = !(fabsf(v) < 1000.0f);
  unsigned long long bb = __ballot(big);
  unsigned int w = eidx[2 * lane + 1];
  unsigned long long bz = __ballot(w == 0u);
  if (lane == 0) {
    flags[0] = (__popcll(bb) < 8) ? 1 : 0;
    flags[1] = (__popcll(bz) == 64) ? 1 : 0;
  }
}

__device__ __forceinline__ int eidx_at(const int* __restrict__ p, int k, int i64) {
  return p[i64 ? (k << 1) : k];
}

// ---------- CSR build ----------
__global__ void k_count(const int* __restrict__ eidx, const int* __restrict__ flags,
                        int* __restrict__ cnt) {
  int e = blockIdx.x * blockDim.x + threadIdx.x;
  if (e >= N_EDGES) return;
  int d = eidx_at(eidx, N_EDGES + e, flags[1]);
  atomicAdd(&cnt[d], 1);
}

// parallel exclusive scan: per-block scan -> scan of block sums -> add offsets
__global__ void k_scan1(const int* __restrict__ cnt, int* __restrict__ rowp,
                        int* __restrict__ bsum) {
  __shared__ int sm[256];
  int t = threadIdx.x, b = blockIdx.x, i = b * 256 + t;
  int v = (i < N_NODES) ? cnt[i] : 0;
  sm[t] = v;
  __syncthreads();
  for (int off = 1; off < 256; off <<= 1) {
    int x = (t >= off) ? sm[t - off] : 0;
    __syncthreads();
    sm[t] += x;
    __syncthreads();
  }
  if (i < N_NODES) rowp[i] = sm[t] - v;  // exclusive, block-local
  if (t == 255) bsum[b] = sm[t];
}

__global__ void k_scan2(int* __restrict__ bsum) {
  __shared__ int sm[256];
  int t = threadIdx.x;
  int v = (t < SCAN_BLOCKS) ? bsum[t] : 0;
  sm[t] = v;
  __syncthreads();
  for (int off = 1; off < 256; off <<= 1) {
    int x = (t >= off) ? sm[t - off] : 0;
    __syncthreads();
    sm[t] += x;
    __syncthreads();
  }
  if (t < SCAN_BLOCKS) bsum[t] = sm[t] - v;  // exclusive block offsets
}

__global__ void k_scan3(int* __restrict__ rowp, const int* __restrict__ bsum) {
  int t = threadIdx.x, b = blockIdx.x, i = b * 256 + t;
  if (i < N_NODES) rowp[i] += bsum[b];
  if (i == 0) rowp[N_NODES] = N_EDGES;
}

// cursor IS a copy of rowp: atomic returns the slot directly (no rowp gather)
__global__ void k_fill(const int* __restrict__ eidx, const int* __restrict__ flags,
                       int* __restrict__ cur_rowp, int* __restrict__ csr) {
  int e = blockIdx.x * blockDim.x + threadIdx.x;
  if (e >= N_EDGES) return;
  int i64 = flags[1];
  int d = eidx_at(eidx, N_EDGES + e, i64);
  int s = eidx_at(eidx, e, i64);
  int pos = atomicAdd(&cur_rowp[d], 1);
  csr[pos] = s;
}

// ---------- h = x@W (h stored bf16), s_src = h@a_s, s_dst = h@a_d (fp32) ----------
__global__ __launch_bounds__(256) void k_gemm(
    const void* __restrict__ xv, int x_raw, const void* __restrict__ Wv,
    const void* __restrict__ asv, const void* __restrict__ adv, int head,
    const int* __restrict__ flags, unsigned short* __restrict__ hb,
    float* __restrict__ ss, float* __restrict__ sd) {
  const int bf = flags[0];
  const int lane = threadIdx.x & 63;
  const int wid = blockIdx.x * (blockDim.x >> 6) + (threadIdx.x >> 6);
  const int nw = gridDim.x * (blockDim.x >> 6);
  float wcol[DIM];
  float a_s, a_d;
  if (bf) {
    const unsigned short* W = (const unsigned short*)Wv + head * DIM * DIM;
    const unsigned short* pa = (const unsigned short*)asv + head * DIM;
    const unsigned short* pd = (const unsigned short*)adv + head * DIM;
#pragma unroll
    for (int k = 0; k < DIM; ++k) wcol[k] = bf2f(W[k * DIM + lane]);
    a_s = bf2f(pa[lane]); a_d = bf2f(pd[lane]);
  } else {
    const float* W = (const float*)Wv + head * DIM * DIM;
    const float* pa = (const float*)asv + head * DIM;
    const float* pd = (const float*)adv + head * DIM;
#pragma unroll
    for (int k = 0; k < DIM; ++k) wcol[k] = W[k * DIM + lane];
    a_s = pa[lane]; a_d = pd[lane];
  }
  const int raw_bf = x_raw && bf;
  for (int row = wid; row < N_NODES; row += nw) {
    float acc = 0.f;
    if (raw_bf) {
      const ushort4* xr = (const ushort4*)((const unsigned short*)xv + row * DIM);
#pragma unroll
      for (int q = 0; q < DIM / 4; ++q) {
        ushort4 xu = xr[q];
        acc = fmaf(bf2f(xu.x), wcol[4 * q + 0], acc);
        acc = fmaf(bf2f(xu.y), wcol[4 * q + 1], acc);
        acc = fmaf(bf2f(xu.z), wcol[4 * q + 2], acc);
        acc = fmaf(bf2f(xu.w), wcol[4 * q + 3], acc);
      }
    } else {
      const float4* xr = (const float4*)((const float*)xv + row * DIM);
#pragma unroll
      for (int q = 0; q < DIM / 4; ++q) {
        float4 xf = xr[q];
        acc = fmaf(xf.x, wcol[4 * q + 0], acc);
        acc = fmaf(xf.y, wcol[4 * q + 1], acc);
        acc = fmaf(xf.z, wcol[4 * q + 2], acc);
        acc = fmaf(xf.w, wcol[4 * q + 3], acc);
      }
    }
    hb[row * DIM + lane] = f2bf(acc);
    float u = acc * a_s, v = acc * a_d;  // scores from fp32 acc (pre-rounding)
#pragma unroll
    for (int off = 32; off > 0; off >>= 1) {
      u += __shfl_xor(u, off);
      v += __shfl_xor(v, off);
    }
    if (lane == 0) { ss[row] = u; sd[row] = v; }
  }
}

// ---------- per-dst-node softmax aggregation (one wave per node) ----------
__global__ __launch_bounds__(256) void k_agg(
    const unsigned short* __restrict__ hb, const float* __restrict__ ss,
    const float* __restrict__ sd, const int* __restrict__ rowp,
    const int* __restrict__ csr, float* __restrict__ out_f,
    void* __restrict__ out_final, const int* __restrict__ flags,
    int do_elu, int is_final) {
  __shared__ __align__(16) float lp[4][64];
  __shared__ __align__(16) int lsrc[4][64];
  const int lane = threadIdx.x & 63;
  const int w = threadIdx.x >> 6;
  const int node = blockIdx.x * 4 + w;
  const int base = rowp[node];
  const int deg = rowp[node + 1] - base;
  const float sdn = sd[node];

  float acc = 0.f, z;
  if (deg <= 64) {
    int s = 0;
    float sc = -INFINITY;
    if (lane < deg) {
      s = csr[base + lane];
      float t = ss[s] + sdn;
      sc = t >= 0.f ? t : 0.2f * t;
    }
    float m = sc;
#pragma unroll
    for (int off = 32; off > 0; off >>= 1) m = fmaxf(m, __shfl_xor(m, off));
    float p = (lane < deg) ? __expf(sc - m) : 0.f;
    z = p;
#pragma unroll
    for (int off = 32; off > 0; off >>= 1) z += __shfl_xor(z, off);
    lp[w][lane] = p;
    lsrc[w][lane] = s;
    __builtin_amdgcn_wave_barrier();
    const int q4 = (deg + 3) >> 2;  // tail p=0, s=0 -> contributes 0
    const float4* lp4 = (const float4*)(&lp[w][0]);
    const int4* ls4 = (const int4*)(&lsrc[w][0]);
    for (int q = 0; q < q4; ++q) {
      float4 pv = lp4[q];
      int4 sv = ls4[q];
      acc = fmaf(pv.x, bf2f(hb[sv.x * DIM + lane]), acc);
      acc = fmaf(pv.y, bf2f(hb[sv.y * DIM + lane]), acc);
      acc = fmaf(pv.z, bf2f(hb[sv.z * DIM + lane]), acc);
      acc = fmaf(pv.w, bf2f(hb[sv.w * DIM + lane]), acc);
    }
    __builtin_amdgcn_wave_barrier();
  } else {
    float m = -INFINITY;
    for (int j = lane; j < deg; j += 64) {
      int s = csr[base + j];
      float sc = ss[s] + sdn;
      sc = sc >= 0.f ? sc : 0.2f * sc;
      m = fmaxf(m, sc);
    }
#pragma unroll
    for (int off = 32; off > 0; off >>= 1) m = fmaxf(m, __shfl_xor(m, off));
    z = 0.f;
    for (int c = 0; c < deg; c += 64) {
      int j = c + lane;
      float p = 0.f; int s = 0;
      if (j < deg) {
        int sv = csr[base + j];
        s = sv;
        float sc = ss[sv] + sdn;
        sc = sc >= 0.f ? sc : 0.2f * sc;
        p = __expf(sc - m);
      }
      lp[w][lane] = p;
      lsrc[w][lane] = s;
      __builtin_amdgcn_wave_barrier();
      z += p;
      const int cl = (deg - c < 64) ? (deg - c) : 64;
      const int q4 = (cl + 3) >> 2;
      const float4* lp4 = (const float4*)(&lp[w][0]);
      const int4* ls4 = (const int4*)(&lsrc[w][0]);
      for (int q = 0; q < q4; ++q) {
        float4 pv = lp4[q];
        int4 sv = ls4[q];
        acc = fmaf(pv.x, bf2f(hb[sv.x * DIM + lane]), acc);
        acc = fmaf(pv.y, bf2f(hb[sv.y * DIM + lane]), acc);
        acc = fmaf(pv.z, bf2f(hb[sv.z * DIM + lane]), acc);
        acc = fmaf(pv.w, bf2f(hb[sv.w * DIM + lane]), acc);
      }
      __builtin_amdgcn_wave_barrier();
    }
#pragma unroll
    for (int off = 32; off > 0; off >>= 1) z += __shfl_xor(z, off);
  }

  float o = acc / (z + 1e-16f);  // deg==0 -> 0, matches reference
  if (do_elu) o = (o > 0.f) ? o : expm1f(o);
  if (is_final) {
    if (flags[0]) ((unsigned short*)out_final)[node * DIM + lane] = f2bf(o);
    else          ((float*)out_final)[node * DIM + lane] = o;
  } else {
    out_f[node * DIM + lane] = o;
  }
}

// ---------- launch ----------
extern "C" void kernel_launch(void* const* d_in, const int* in_sizes, int n_in,
                              void* d_out, int out_size, void* d_ws, size_t ws_size,
                              hipStream_t stream) {
  const void* feat = d_in[0];
  const int* eidx = (const int*)d_in[1];

  float* bufA = (float*)d_ws;                      // N*64 fp32
  float* bufB = bufA + N_NODES * DIM;              // N*64 fp32
  unsigned short* hb = (unsigned short*)(bufB + N_NODES * DIM);  // N*64 bf16
  float* ssrc = (float*)(hb + N_NODES * DIM);      // N
  float* sdst = ssrc + N_NODES;                    // N
  int* rowp = (int*)(sdst + N_NODES);              // N+1
  int* rcur = rowp + N_NODES + 1;                  // N+1 (cursor copy)
  int* cnt  = rcur + N_NODES + 1;                  // N
  int* csr  = cnt + N_NODES;                       // E
  int* bsum = csr + N_EDGES;                       // SCAN_BLOCKS
  int* flags = bsum + SCAN_BLOCKS;                 // 2

  k_detect<<<1, 64, 0, stream>>>((const unsigned short*)feat,
                                 (const unsigned int*)eidx, flags);
  (void)hipMemsetAsync(cnt, 0, N_NODES * sizeof(int), stream);
  k_count<<<(N_EDGES + 255) / 256, 256, 0, stream>>>(eidx, flags, cnt);
  k_scan1<<<SCAN_BLOCKS, 256, 0, stream>>>(cnt, rowp, bsum);
  k_scan2<<<1, 256, 0, stream>>>(bsum);
  k_scan3<<<SCAN_BLOCKS, 256, 0, stream>>>(rowp, bsum);
  (void)hipMemcpyAsync(rcur, rowp, (N_NODES + 1) * sizeof(int),
                       hipMemcpyDeviceToDevice, stream);
  k_fill<<<(N_EDGES + 255) / 256, 256, 0, stream>>>(eidx, flags, rcur, csr);

  const void* xcur = feat;
  int x_raw = 1;
  float* nxt = bufA;
  float* other = bufB;
  for (int i = 0; i < 8; ++i) {
    const void* Wb = (i < 4) ? d_in[2] : d_in[5];
    const void* ab = (i < 4) ? d_in[3] : d_in[6];
    const void* db = (i < 4) ? d_in[4] : d_in[7];
    int head = i & 3;
    k_gemm<<<1024, 256, 0, stream>>>(xcur, x_raw, Wb, ab, db, head, flags,
                                     hb, ssrc, sdst);
    int elu = (i == 3 || i == 7) ? 1 : 0;
    int fin = (i == 7) ? 1 : 0;
    k_agg<<<N_NODES / 4, 256, 0, stream>>>(hb, ssrc, sdst, rowp, csr, nxt,
                                           d_out, flags, elu, fin);
    xcur = nxt; x_raw = 0;
    float* t = nxt; nxt = other; other = t;
  }
}

// Round 4
// 568.257 us; speedup vs baseline: 1.3640x; 1.1046x over previous
//
#include <hip/hip_runtime.h>
#include <hip/hip_bf16.h>

#define N_NODES 50000
#define N_EDGES 800000
#define DIM 64
#define NB 391      // dst buckets of 128 nodes: ceil(50000/128)
#define NBLK 128    // blocks in bucketize pass
#define CHUNK 6250  // N_EDGES / NBLK (exact)
#define CAP 4096    // LDS staging capacity per bucket segment (avg ~2048)

// ---------- helpers ----------
__device__ __forceinline__ float bf2f(unsigned short u) {
  return __uint_as_float(((unsigned int)u) << 16);
}
__device__ __forceinline__ unsigned short f2bf(float f) {
  unsigned int x = __float_as_uint(f);
  unsigned int r = (x + 0x7fffu + ((x >> 16) & 1u)) >> 16;  // RNE
  return (unsigned short)r;
}

// ---------- dtype detection (flags[0]=bf16 inputs, flags[1]=int64 indices) ----------
__global__ void k_detect(const unsigned short* __restrict__ feat,
                         const unsigned int* __restrict__ eidx,
                         int* __restrict__ flags) {
  int lane = threadIdx.x;  // 64 threads
  float v = bf2f(feat[2 * lane]);
  bool big = !(fabsf(v) < 1000.0f);
  unsigned long long bb = __ballot(big);
  unsigned int w = eidx[2 * lane + 1];
  unsigned long long bz = __ballot(w == 0u);
  if (lane == 0) {
    flags[0] = (__popcll(bb) < 8) ? 1 : 0;
    flags[1] = (__popcll(bz) == 64) ? 1 : 0;
  }
}

__device__ __forceinline__ int eidx_at(const int* __restrict__ p, int k, int i64) {
  return p[i64 ? (k << 1) : k];
}

// ---------- generalized scan (n <= 65536): per-block scan -> block sums -> add ----------
__global__ void k_scan1(const int* __restrict__ in, int* __restrict__ out,
                        int* __restrict__ bsum, int n) {
  __shared__ int sm[256];
  int t = threadIdx.x, b = blockIdx.x, i = b * 256 + t;
  int v = (i < n) ? in[i] : 0;
  sm[t] = v;
  __syncthreads();
  for (int off = 1; off < 256; off <<= 1) {
    int x = (t >= off) ? sm[t - off] : 0;
    __syncthreads();
    sm[t] += x;
    __syncthreads();
  }
  if (i < n) out[i] = sm[t] - v;  // exclusive, block-local
  if (t == 255) bsum[b] = sm[t];
}

__global__ void k_scan2(int* __restrict__ bsum, int nb) {
  __shared__ int sm[256];
  int t = threadIdx.x;
  int v = (t < nb) ? bsum[t] : 0;
  sm[t] = v;
  __syncthreads();
  for (int off = 1; off < 256; off <<= 1) {
    int x = (t >= off) ? sm[t - off] : 0;
    __syncthreads();
    sm[t] += x;
    __syncthreads();
  }
  if (t < nb) bsum[t] = sm[t] - v;
}

__global__ void k_scan3(int* __restrict__ out, const int* __restrict__ bsum,
                        int n, int total, int append) {
  int t = threadIdx.x, b = blockIdx.x, i = b * 256 + t;
  if (i < n) out[i] += bsum[b];
  if (i == 0 && append) out[n] = total;
}

// ---------- bucketed CSR build ----------
// pass A1: per-(bucket,block) histogram, bucket = dst >> 7
__global__ __launch_bounds__(256) void k_hist1(const int* __restrict__ eidx,
                                               const int* __restrict__ flags,
                                               int* __restrict__ hist) {
  __shared__ int h[NB];
  int t = threadIdx.x, b = blockIdx.x;
  for (int i = t; i < NB; i += 256) h[i] = 0;
  __syncthreads();
  int i64 = flags[1];
  int lo = b * CHUNK;
  for (int i = t; i < CHUNK; i += 256) {
    int d = eidx_at(eidx, N_EDGES + lo + i, i64);
    atomicAdd(&h[d >> 7], 1);
  }
  __syncthreads();
  for (int i = t; i < NB; i += 256) hist[i * NBLK + b] = h[i];
}

// pass A2: scatter (src,dst) pairs bucket-major into ebuf (per-block LDS cursors)
__global__ __launch_bounds__(256) void k_scatter(const int* __restrict__ eidx,
                                                 const int* __restrict__ flags,
                                                 const int* __restrict__ hscan,
                                                 int2* __restrict__ ebuf) {
  __shared__ int cur[NB];
  int t = threadIdx.x, b = blockIdx.x;
  for (int i = t; i < NB; i += 256) cur[i] = hscan[i * NBLK + b];
  __syncthreads();
  int i64 = flags[1];
  int lo = b * CHUNK;
  for (int i = t; i < CHUNK; i += 256) {
    int d = eidx_at(eidx, N_EDGES + lo + i, i64);
    int s = eidx_at(eidx, lo + i, i64);
    int pos = atomicAdd(&cur[d >> 7], 1);
    ebuf[pos] = make_int2(s, d);
  }
}

// pass B1: exact per-dst degree via LDS histogram (replaces global-atomic count)
__global__ __launch_bounds__(256) void k_cnt2(const int2* __restrict__ ebuf,
                                              const int* __restrict__ hscan,
                                              int* __restrict__ cnt) {
  __shared__ int h[128];
  int t = threadIdx.x, b = blockIdx.x;  // b in [0, NB)
  if (t < 128) h[t] = 0;
  __syncthreads();
  int lo = hscan[b * NBLK];
  int hi = (b + 1 < NB) ? hscan[(b + 1) * NBLK] : N_EDGES;
  for (int i = lo + t; i < hi; i += 256) atomicAdd(&h[ebuf[i].y & 127], 1);
  __syncthreads();
  int d = b * 128 + t;
  if (t < 128 && d < N_NODES) cnt[d] = h[t];
}

// pass B2: place each bucket's CSR segment in LDS, flush coalesced
__global__ __launch_bounds__(256) void k_place(const int2* __restrict__ ebuf,
                                               const int* __restrict__ hscan,
                                               const int* __restrict__ rowp,
                                               int* __restrict__ csr) {
  __shared__ int cur[128];
  __shared__ int lcsr[CAP];
  int t = threadIdx.x, b = blockIdx.x;
  int lo = hscan[b * NBLK];
  int hi = (b + 1 < NB) ? hscan[(b + 1) * NBLK] : N_EDGES;
  int d0 = b * 128;
  int dmax = d0 + 128; if (dmax > N_NODES) dmax = N_NODES;
  int seg_lo = rowp[d0];
  int seg_hi = rowp[dmax];
  int seg_sz = seg_hi - seg_lo;
  if (seg_sz <= CAP) {
    if (t < 128) cur[t] = ((d0 + t < dmax) ? rowp[d0 + t] : seg_hi) - seg_lo;
    __syncthreads();
    for (int i = lo + t; i < hi; i += 256) {
      int2 pr = ebuf[i];
      int pos = atomicAdd(&cur[pr.y & 127], 1);
      lcsr[pos] = pr.x;
    }
    __syncthreads();
    for (int i = t; i < seg_sz; i += 256) csr[seg_lo + i] = lcsr[i];
  } else {  // overflow fallback (astronomically unlikely, but deterministic)
    if (t < 128) cur[t] = (d0 + t < dmax) ? rowp[d0 + t] : 0;
    __syncthreads();
    for (int i = lo + t; i < hi; i += 256) {
      int2 pr = ebuf[i];
      int pos = atomicAdd(&cur[pr.y & 127], 1);
      csr[pos] = pr.x;
    }
  }
}

// ---------- h = x@W (h stored bf16), s_src = h@a_s, s_dst = h@a_d (fp32) ----------
__global__ __launch_bounds__(256) void k_gemm(
    const void* __restrict__ xv, int x_raw, const void* __restrict__ Wv,
    const void* __restrict__ asv, const void* __restrict__ adv, int head,
    const int* __restrict__ flags, unsigned short* __restrict__ hb,
    float* __restrict__ ss, float* __restrict__ sd) {
  const int bf = flags[0];
  const int lane = threadIdx.x & 63;
  const int wid = blockIdx.x * (blockDim.x >> 6) + (threadIdx.x >> 6);
  const int nw = gridDim.x * (blockDim.x >> 6);
  float wcol[DIM];
  float a_s, a_d;
  if (bf) {
    const unsigned short* W = (const unsigned short*)Wv + head * DIM * DIM;
    const unsigned short* pa = (const unsigned short*)asv + head * DIM;
    const unsigned short* pd = (const unsigned short*)adv + head * DIM;
#pragma unroll
    for (int k = 0; k < DIM; ++k) wcol[k] = bf2f(W[k * DIM + lane]);
    a_s = bf2f(pa[lane]); a_d = bf2f(pd[lane]);
  } else {
    const float* W = (const float*)Wv + head * DIM * DIM;
    const float* pa = (const float*)asv + head * DIM;
    const float* pd = (const float*)adv + head * DIM;
#pragma unroll
    for (int k = 0; k < DIM; ++k) wcol[k] = W[k * DIM + lane];
    a_s = pa[lane]; a_d = pd[lane];
  }
  const int raw_bf = x_raw && bf;
  for (int row = wid; row < N_NODES; row += nw) {
    float acc = 0.f;
    if (raw_bf) {
      const ushort4* xr = (const ushort4*)((const unsigned short*)xv + row * DIM);
#pragma unroll
      for (int q = 0; q < DIM / 4; ++q) {
        ushort4 xu = xr[q];
        acc = fmaf(bf2f(xu.x), wcol[4 * q + 0], acc);
        acc = fmaf(bf2f(xu.y), wcol[4 * q + 1], acc);
        acc = fmaf(bf2f(xu.z), wcol[4 * q + 2], acc);
        acc = fmaf(bf2f(xu.w), wcol[4 * q + 3], acc);
      }
    } else {
      const float4* xr = (const float4*)((const float*)xv + row * DIM);
#pragma unroll
      for (int q = 0; q < DIM / 4; ++q) {
        float4 xf = xr[q];
        acc = fmaf(xf.x, wcol[4 * q + 0], acc);
        acc = fmaf(xf.y, wcol[4 * q + 1], acc);
        acc = fmaf(xf.z, wcol[4 * q + 2], acc);
        acc = fmaf(xf.w, wcol[4 * q + 3], acc);
      }
    }
    hb[row * DIM + lane] = f2bf(acc);
    float u = acc * a_s, v = acc * a_d;  // scores from fp32 acc (pre-rounding)
#pragma unroll
    for (int off = 32; off > 0; off >>= 1) {
      u += __shfl_xor(u, off);
      v += __shfl_xor(v, off);
    }
    if (lane == 0) { ss[row] = u; sd[row] = v; }
  }
}

// ---------- per-dst-node softmax aggregation (one wave per node) ----------
// pair-gather: lanes 0-31 gather even edge's h-row, lanes 32-63 the odd edge;
// each lane loads 2 cols (ushort2) -> 256 B & 2 edges per load instruction.
__device__ __forceinline__ void pair_accum(const unsigned short* __restrict__ hb,
                                           const int2* __restrict__ lps, int cl,
                                           int half, int col2, float2& acc) {
  const int pairs = (cl + 1) >> 1;
#pragma unroll 4
  for (int tt = 0; tt < pairs; ++tt) {
    int j = 2 * tt + half;  // tail entry has p=0,s=0 -> contributes 0
    int2 pv = lps[j];       // LDS same-address broadcast within half-wave
    float pj = __int_as_float(pv.x);
    int sj = pv.y;
    ushort2 hv = *(const ushort2*)(hb + sj * DIM + 2 * col2);
    acc.x = fmaf(pj, bf2f(hv.x), acc.x);
    acc.y = fmaf(pj, bf2f(hv.y), acc.y);
  }
}

__global__ __launch_bounds__(256) void k_agg(
    const unsigned short* __restrict__ hb, const float* __restrict__ ss,
    const float* __restrict__ sd, const int* __restrict__ rowp,
    const int* __restrict__ csr, float* __restrict__ out_f,
    void* __restrict__ out_final, const int* __restrict__ flags,
    int do_elu, int is_final) {
  __shared__ __align__(16) int2 lps[4][64];  // {p bits, src}
  const int lane = threadIdx.x & 63;
  const int half = lane >> 5;
  const int col2 = lane & 31;  // this lane covers cols 2*col2, 2*col2+1
  const int w = threadIdx.x >> 6;
  const int node = blockIdx.x * 4 + w;
  const int base = rowp[node];
  const int deg = rowp[node + 1] - base;
  const float sdn = sd[node];

  float2 acc = {0.f, 0.f};
  float z;
  if (deg <= 64) {
    int s = 0;
    float sc = -INFINITY;
    if (lane < deg) {
      s = csr[base + lane];
      float t = ss[s] + sdn;
      sc = t >= 0.f ? t : 0.2f * t;
    }
    float m = sc;
#pragma unroll
    for (int off = 32; off > 0; off >>= 1) m = fmaxf(m, __shfl_xor(m, off));
    float p = (lane < deg) ? __expf(sc - m) : 0.f;
    z = p;
#pragma unroll
    for (int off = 32; off > 0; off >>= 1) z += __shfl_xor(z, off);
    lps[w][lane] = make_int2(__float_as_int(p), s);
    __builtin_amdgcn_wave_barrier();
    pair_accum(hb, &lps[w][0], deg, half, col2, acc);
    __builtin_amdgcn_wave_barrier();
  } else {
    float m = -INFINITY;
    for (int j = lane; j < deg; j += 64) {
      int s = csr[base + j];
      float sc = ss[s] + sdn;
      sc = sc >= 0.f ? sc : 0.2f * sc;
      m = fmaxf(m, sc);
    }
#pragma unroll
    for (int off = 32; off > 0; off >>= 1) m = fmaxf(m, __shfl_xor(m, off));
    z = 0.f;
    for (int c = 0; c < deg; c += 64) {
      int j = c + lane;
      float p = 0.f; int s = 0;
      if (j < deg) {
        s = csr[base + j];
        float sc = ss[s] + sdn;
        sc = sc >= 0.f ? sc : 0.2f * sc;
        p = __expf(sc - m);
      }
      lps[w][lane] = make_int2(__float_as_int(p), s);
      __builtin_amdgcn_wave_barrier();
      z += p;
      const int cl = (deg - c < 64) ? (deg - c) : 64;
      pair_accum(hb, &lps[w][0], cl, half, col2, acc);
      __builtin_amdgcn_wave_barrier();
    }
#pragma unroll
    for (int off = 32; off > 0; off >>= 1) z += __shfl_xor(z, off);
  }

  // combine the two half-wave partial sums (same cols, disjoint edges)
  acc.x += __shfl_xor(acc.x, 32);
  acc.y += __shfl_xor(acc.y, 32);

  float inv = 1.f / (z + 1e-16f);  // deg==0 -> 0, matches reference
  float ox = acc.x * inv, oy = acc.y * inv;
  if (do_elu) {
    ox = (ox > 0.f) ? ox : expm1f(ox);
    oy = (oy > 0.f) ? oy : expm1f(oy);
  }
  if (half == 0) {
    if (is_final) {
      if (flags[0]) {
        ushort2 o2 = {f2bf(ox), f2bf(oy)};
        *(ushort2*)((unsigned short*)out_final + node * DIM + 2 * col2) = o2;
      } else {
        float2 o2 = {ox, oy};
        *(float2*)((float*)out_final + node * DIM + 2 * col2) = o2;
      }
    } else {
      float2 o2 = {ox, oy};
      *(float2*)(out_f + node * DIM + 2 * col2) = o2;
    }
  }
}

// ---------- launch ----------
extern "C" void kernel_launch(void* const* d_in, const int* in_sizes, int n_in,
                              void* d_out, int out_size, void* d_ws, size_t ws_size,
                              hipStream_t stream) {
  const void* feat = d_in[0];
  const int* eidx = (const int*)d_in[1];

  float* bufA = (float*)d_ws;                                    // N*64 f32
  float* bufB = bufA + N_NODES * DIM;                            // N*64 f32
  unsigned short* hb = (unsigned short*)(bufB + N_NODES * DIM);  // N*64 bf16
  int2* ebuf = (int2*)(hb + N_NODES * DIM);                      // E int2 (8B-aligned)
  float* ssrc = (float*)(ebuf + N_EDGES);                        // N
  float* sdst = ssrc + N_NODES;                                  // N
  int* rowp = (int*)(sdst + N_NODES);                            // N+1
  int* cnt  = rowp + N_NODES + 1;                                // N
  int* csr  = cnt + N_NODES;                                     // E
  int* hist = csr + N_EDGES;                                     // NB*NBLK
  int* hscan = hist + NB * NBLK;                                 // NB*NBLK
  int* bsum = hscan + NB * NBLK;                                 // 256
  int* flags = bsum + 256;                                       // 2

  const int NH = NB * NBLK;                 // 50048
  const int SBH = (NH + 255) / 256;         // 196
  const int SBN = (N_NODES + 255) / 256;    // 196

  k_detect<<<1, 64, 0, stream>>>((const unsigned short*)feat,
                                 (const unsigned int*)eidx, flags);
  k_hist1<<<NBLK, 256, 0, stream>>>(eidx, flags, hist);
  k_scan1<<<SBH, 256, 0, stream>>>(hist, hscan, bsum, NH);
  k_scan2<<<1, 256, 0, stream>>>(bsum, SBH);
  k_scan3<<<SBH, 256, 0, stream>>>(hscan, bsum, NH, 0, 0);
  k_scatter<<<NBLK, 256, 0, stream>>>(eidx, flags, hscan, ebuf);
  k_cnt2<<<NB, 256, 0, stream>>>(ebuf, hscan, cnt);
  k_scan1<<<SBN, 256, 0, stream>>>(cnt, rowp, bsum, N_NODES);
  k_scan2<<<1, 256, 0, stream>>>(bsum, SBN);
  k_scan3<<<SBN, 256, 0, stream>>>(rowp, bsum, N_NODES, N_EDGES, 1);
  k_place<<<NB, 256, 0, stream>>>(ebuf, hscan, rowp, csr);

  const void* xcur = feat;
  int x_raw = 1;
  float* nxt = bufA;
  float* other = bufB;
  for (int i = 0; i < 8; ++i) {
    const void* Wb = (i < 4) ? d_in[2] : d_in[5];
    const void* ab = (i < 4) ? d_in[3] : d_in[6];
    const void* db = (i < 4) ? d_in[4] : d_in[7];
    int head = i & 3;
    k_gemm<<<1024, 256, 0, stream>>>(xcur, x_raw, Wb, ab, db, head, flags,
                                     hb, ssrc, sdst);
    int elu = (i == 3 || i == 7) ? 1 : 0;
    int fin = (i == 7) ? 1 : 0;
    k_agg<<<N_NODES / 4, 256, 0, stream>>>(hb, ssrc, sdst, rowp, csr, nxt,
                                           d_out, flags, elu, fin);
    xcur = nxt; x_raw = 0;
    float* t = nxt; nxt = other; other = t;
  }
}